// Round 1
// baseline (614.137 us; speedup 1.0000x reference)
//
#include <hip/hip_runtime.h>

#define B_  4
#define S_  2048
#define D_  1024
#define F_  4096
#define E_  8
#define C_  320
#define CP_ 384            // padded capacity (3 x 128 tiles)
#define NT_ (B_*S_)        // 8192 tokens
#define G_  (B_*E_)        // 32 (batch, expert) groups

typedef short bf16x8 __attribute__((ext_vector_type(8)));
typedef float f32x4  __attribute__((ext_vector_type(4)));

using gptr_t = const __attribute__((address_space(1))) void*;
using lptr_t = __attribute__((address_space(3))) void*;

__device__ static inline void gll16(const void* g, void* l) {
    __builtin_amdgcn_global_load_lds((gptr_t)g, (lptr_t)l, 16, 0, 0);
}

// fp32 -> bf16 round-to-nearest-even (finite inputs only)
__device__ static inline unsigned short f2b(float f) {
    unsigned int u = __float_as_uint(f);
    u += 0x7fffu + ((u >> 16) & 1u);
    return (unsigned short)(u >> 16);
}

// ---------------- weight transpose + fp32->bf16 ----------------
// in: [e][R][Cc] fp32 row-major ; out: [e][Cc][R] bf16 row-major
__global__ __launch_bounds__(256) void k_transpose(const float* __restrict__ in,
                                                   unsigned short* __restrict__ out,
                                                   int R, int Cc) {
    __shared__ unsigned short tile[32][33];
    int e = blockIdx.z;
    const float* src = in + (size_t)e * R * Cc;
    unsigned short* dst = out + (size_t)e * R * Cc;
    int c0 = blockIdx.x * 32, r0 = blockIdx.y * 32;
    int tx = threadIdx.x & 31, ty = threadIdx.x >> 5;
#pragma unroll
    for (int i = 0; i < 32; i += 8)
        tile[ty + i][tx] = f2b(src[(size_t)(r0 + ty + i) * Cc + c0 + tx]);
    __syncthreads();
#pragma unroll
    for (int i = 0; i < 32; i += 8)
        dst[(size_t)(c0 + ty + i) * R + r0 + tx] = tile[tx][ty + i];
}

// ---------------- router: logits + softmax top-1 ----------------
__global__ __launch_bounds__(256) void k_router(const float* __restrict__ hs,
                                                const float* __restrict__ gw,
                                                float* __restrict__ logits,
                                                int* __restrict__ eidx,
                                                float* __restrict__ tp) {
    int tok  = (int)((blockIdx.x * 256 + threadIdx.x) >> 6);   // one wave per token
    int lane = threadIdx.x & 63;
    const float* x = hs + (size_t)tok * D_;
    double acc[E_];
#pragma unroll
    for (int e = 0; e < E_; e++) acc[e] = 0.0;
    for (int i = 0; i < 16; i++) {
        float xv = x[lane + 64 * i];
#pragma unroll
        for (int e = 0; e < E_; e++)
            acc[e] += (double)xv * (double)gw[e * D_ + lane + 64 * i];
    }
#pragma unroll
    for (int e = 0; e < E_; e++) {
#pragma unroll
        for (int off = 32; off > 0; off >>= 1)
            acc[e] += __shfl_xor(acc[e], off, 64);
    }
    if (lane == 0) {
        float l[E_];
        float mx = -1e30f; int am = 0;
#pragma unroll
        for (int e = 0; e < E_; e++) {
            l[e] = (float)acc[e];
            if (l[e] > mx) { mx = l[e]; am = e; }   // strict > : first max wins (matches argmax)
        }
        float se = 0.f;
#pragma unroll
        for (int e = 0; e < E_; e++) se += __expf(l[e] - mx);
        tp[tok]   = 1.0f / se;     // top prob = exp(mx-mx)/sum
        eidx[tok] = am;
#pragma unroll
        for (int e = 0; e < E_; e++) logits[(size_t)tok * E_ + e] = l[e];
    }
}

// ---------------- capacity scan: slot assignment per batch ----------------
__global__ __launch_bounds__(256) void k_scan(const int* __restrict__ eidx,
                                              int* __restrict__ slot,
                                              int* __restrict__ tok_list,
                                              int* __restrict__ counts,
                                              float* __restrict__ eif) {
    int b = blockIdx.x;
    __shared__ int cCnt[32][E_];
    __shared__ int cBase[32][E_];
    int t = threadIdx.x, wv = t >> 6, lane = t & 63;
    const int* eb = eidx + b * S_;
    // phase A: per-64-token-chunk expert counts via ballot
    for (int c = wv; c < 32; c += 4) {
        int e = eb[c * 64 + lane];
#pragma unroll
        for (int x = 0; x < E_; x++) {
            unsigned long long m = __ballot(e == x);
            if (lane == 0) cCnt[c][x] = __popcll(m);
        }
    }
    __syncthreads();
    // phase B: exclusive scan over chunks, one expert per lane
    if (t < E_) {
        int s = 0;
        for (int c = 0; c < 32; c++) { cBase[c][t] = s; s += cCnt[c][t]; }
        counts[b * E_ + t] = s;
    }
    __syncthreads();
    // phase C: final slot = chunk base + within-chunk rank
    for (int c = wv; c < 32; c += 4) {
        int s_tok = c * 64 + lane;
        int e = eb[s_tok];
        unsigned long long lowmask = (1ull << lane) - 1ull;
        int rank = 0;
#pragma unroll
        for (int x = 0; x < E_; x++) {
            unsigned long long m = __ballot(e == x);
            if (x == e) rank = __popcll(m & lowmask);
        }
        int pos = cBase[c][e] + rank;
        int assigned = (pos < C_);
        slot[b * S_ + s_tok] = assigned ? pos : C_;
        if (assigned) tok_list[(b * E_ + e) * C_ + pos] = s_tok;
        eif[b * S_ + s_tok] = assigned ? (float)e : 0.0f;
    }
}

// ---------------- dispatch: gather tokens -> bf16 Xd[g][CP_][D_] ----------------
__global__ __launch_bounds__(256) void k_dispatch(const float* __restrict__ hs,
                                                  const int* __restrict__ tok_list,
                                                  const int* __restrict__ counts,
                                                  unsigned short* __restrict__ Xd) {
    int w    = (int)((blockIdx.x * 256 + threadIdx.x) >> 6);  // one wave per row
    int lane = threadIdx.x & 63;
    int g = w / CP_, row = w % CP_;
    int b = g >> 3;
    int n = min(counts[g], C_);
    unsigned short* drow = Xd + ((size_t)g * CP_ + row) * D_;
    if (row < n) {
        int ts = tok_list[g * C_ + row];
        const float* src = hs + ((size_t)b * S_ + ts) * D_;
#pragma unroll
        for (int i = 0; i < 2; i++) {
            int c0 = (lane + 64 * i) * 8;
            float4 v0 = *(const float4*)(src + c0);
            float4 v1 = *(const float4*)(src + c0 + 4);
            uint4 pk;
            pk.x = (unsigned)f2b(v0.x) | ((unsigned)f2b(v0.y) << 16);
            pk.y = (unsigned)f2b(v0.z) | ((unsigned)f2b(v0.w) << 16);
            pk.z = (unsigned)f2b(v1.x) | ((unsigned)f2b(v1.y) << 16);
            pk.w = (unsigned)f2b(v1.z) | ((unsigned)f2b(v1.w) << 16);
            *(uint4*)(drow + c0) = pk;
        }
    } else {
        uint4 z = {0u, 0u, 0u, 0u};
#pragma unroll
        for (int i = 0; i < 2; i++)
            *(uint4*)(drow + (lane + 64 * i) * 8) = z;
    }
}

// ---------------- GEMM1: h = silu(Xd @ w1t^T) , bf16 out ----------------
// A: Xd[g] (CP_ x D_), B: w1t[e] ([n=F_][k=D_], k-contiguous), C: h[g] (CP_ x F_)
__global__ __launch_bounds__(256) void k_ffn1(const unsigned short* __restrict__ Xd,
                                              const unsigned short* __restrict__ w1t,
                                              const int* __restrict__ counts,
                                              unsigned short* __restrict__ h) {
    int g = blockIdx.z;
    int n_tok = min(counts[g], C_);
    int m0 = blockIdx.y * 128;
    if (m0 >= n_tok) return;               // block-uniform early exit
    int n0 = blockIdx.x * 128;
    int e = g & 7;

    __shared__ unsigned short As[128 * 32];
    __shared__ unsigned short Bs[128 * 32];
    int t = threadIdx.x, lane = t & 63, wv = t >> 6, wm = wv >> 1, wn = wv & 1;

    const unsigned short* Ap = Xd  + (size_t)g * CP_ * D_ + (size_t)(m0 + (t >> 2)) * D_ + (t & 3) * 8;
    const unsigned short* Bp = w1t + (size_t)e * F_ * D_  + (size_t)(n0 + (t >> 2)) * D_ + (t & 3) * 8;

    f32x4 acc[4][4];
    f32x4 z = {0.f, 0.f, 0.f, 0.f};
#pragma unroll
    for (int i = 0; i < 4; i++)
#pragma unroll
        for (int j = 0; j < 4; j++) acc[i][j] = z;

    int ar = (wm * 64 + (lane & 15)) * 32 + (lane >> 4) * 8;
    int br = (wn * 64 + (lane & 15)) * 32 + (lane >> 4) * 8;

    for (int kt = 0; kt < D_; kt += 32) {
        __syncthreads();
        gll16(Ap,            (char*)As + wv * 1024);
        gll16(Ap + 64 * D_,  (char*)As + 4096 + wv * 1024);
        gll16(Bp,            (char*)Bs + wv * 1024);
        gll16(Bp + 64 * D_,  (char*)Bs + 4096 + wv * 1024);
        Ap += 32; Bp += 32;
        __syncthreads();
        bf16x8 a[4], bq[4];
#pragma unroll
        for (int i = 0; i < 4; i++) a[i]  = *(const bf16x8*)&As[ar + i * 512];
#pragma unroll
        for (int j = 0; j < 4; j++) bq[j] = *(const bf16x8*)&Bs[br + j * 512];
#pragma unroll
        for (int i = 0; i < 4; i++)
#pragma unroll
            for (int j = 0; j < 4; j++)
                acc[i][j] = __builtin_amdgcn_mfma_f32_16x16x32_bf16(a[i], bq[j], acc[i][j], 0, 0, 0);
    }

    unsigned short* hb = h + (size_t)g * CP_ * F_;
    int crow = m0 + wm * 64 + (lane >> 4) * 4;
    int ccol = n0 + wn * 64 + (lane & 15);
#pragma unroll
    for (int i = 0; i < 4; i++)
#pragma unroll
        for (int r = 0; r < 4; r++) {
            int row = crow + i * 16 + r;
#pragma unroll
            for (int j = 0; j < 4; j++) {
                float v = acc[i][j][r];
                v = v / (1.0f + __expf(-v));        // silu
                hb[(size_t)row * F_ + ccol + j * 16] = f2b(v);
            }
        }
}

// ---------------- GEMM2: y = h @ w2t^T, scale by top_prob, scatter ----------------
__global__ __launch_bounds__(256) void k_ffn2(const unsigned short* __restrict__ h,
                                              const unsigned short* __restrict__ w2t,
                                              const int* __restrict__ counts,
                                              const int* __restrict__ tok_list,
                                              const float* __restrict__ tp,
                                              float* __restrict__ out) {
    int g = blockIdx.z;
    int n_tok = min(counts[g], C_);
    int m0 = blockIdx.y * 128;
    if (m0 >= n_tok) return;
    int n0 = blockIdx.x * 128;
    int b = g >> 3, e = g & 7;

    __shared__ unsigned short As[128 * 32];
    __shared__ unsigned short Bs[128 * 32];
    int t = threadIdx.x, lane = t & 63, wv = t >> 6, wm = wv >> 1, wn = wv & 1;

    const unsigned short* Ap = h   + (size_t)g * CP_ * F_ + (size_t)(m0 + (t >> 2)) * F_ + (t & 3) * 8;
    const unsigned short* Bp = w2t + (size_t)e * D_ * F_  + (size_t)(n0 + (t >> 2)) * F_ + (t & 3) * 8;

    f32x4 acc[4][4];
    f32x4 z = {0.f, 0.f, 0.f, 0.f};
#pragma unroll
    for (int i = 0; i < 4; i++)
#pragma unroll
        for (int j = 0; j < 4; j++) acc[i][j] = z;

    int ar = (wm * 64 + (lane & 15)) * 32 + (lane >> 4) * 8;
    int br = (wn * 64 + (lane & 15)) * 32 + (lane >> 4) * 8;

    for (int kt = 0; kt < F_; kt += 32) {
        __syncthreads();
        gll16(Ap,            (char*)As + wv * 1024);
        gll16(Ap + 64 * F_,  (char*)As + 4096 + wv * 1024);
        gll16(Bp,            (char*)Bs + wv * 1024);
        gll16(Bp + 64 * F_,  (char*)Bs + 4096 + wv * 1024);
        Ap += 32; Bp += 32;
        __syncthreads();
        bf16x8 a[4], bq[4];
#pragma unroll
        for (int i = 0; i < 4; i++) a[i]  = *(const bf16x8*)&As[ar + i * 512];
#pragma unroll
        for (int j = 0; j < 4; j++) bq[j] = *(const bf16x8*)&Bs[br + j * 512];
#pragma unroll
        for (int i = 0; i < 4; i++)
#pragma unroll
            for (int j = 0; j < 4; j++)
                acc[i][j] = __builtin_amdgcn_mfma_f32_16x16x32_bf16(a[i], bq[j], acc[i][j], 0, 0, 0);
    }

    int crow = m0 + wm * 64 + (lane >> 4) * 4;
    int ccol = n0 + wn * 64 + (lane & 15);
#pragma unroll
    for (int i = 0; i < 4; i++)
#pragma unroll
        for (int r = 0; r < 4; r++) {
            int row = crow + i * 16 + r;
            if (row < n_tok) {
                int ts = tok_list[g * C_ + row];
                float sc = tp[b * S_ + ts];
                float* orow = out + ((size_t)b * S_ + ts) * D_ + ccol;
#pragma unroll
                for (int j = 0; j < 4; j++)
                    orow[j * 16] = sc * acc[i][j][r];
            }
        }
}

// ---------------- passthrough for dropped tokens ----------------
__global__ __launch_bounds__(256) void k_pass(const float* __restrict__ hs,
                                              const int* __restrict__ slot,
                                              const float* __restrict__ tp,
                                              float* __restrict__ out) {
    int tok  = (int)((blockIdx.x * 256 + threadIdx.x) >> 6);
    int lane = threadIdx.x & 63;
    if (slot[tok] < C_) return;            // assigned: written by k_ffn2
    float sc = tp[tok];
    const float* src = hs + (size_t)tok * D_;
    float* dst = out + (size_t)tok * D_;
#pragma unroll
    for (int i = 0; i < 4; i++) {
        float4 v = *(const float4*)(src + (lane + 64 * i) * 4);
        v.x *= sc; v.y *= sc; v.z *= sc; v.w *= sc;
        *(float4*)(dst + (lane + 64 * i) * 4) = v;
    }
}

extern "C" void kernel_launch(void* const* d_in, const int* in_sizes, int n_in,
                              void* d_out, int out_size, void* d_ws, size_t ws_size,
                              hipStream_t stream) {
    const float* hs = (const float*)d_in[0];
    const float* gw = (const float*)d_in[1];
    const float* w1 = (const float*)d_in[2];
    const float* w2 = (const float*)d_in[3];

    float* out    = (float*)d_out;                       // [B,S,D] fp32
    float* logits = out + (size_t)NT_ * D_;              // [B,S,E] fp32
    float* eif    = logits + (size_t)NT_ * E_;           // [B,S]   (expert idx as float)

    char* ws = (char*)d_ws;
    int*            eidx     = (int*)(ws + 0);                         //  32 KB
    int*            slot     = (int*)(ws + 65536);                     //  32 KB
    float*          tp       = (float*)(ws + 131072);                  //  32 KB
    int*            tok_list = (int*)(ws + 196608);                    //  40 KB
    int*            counts   = (int*)(ws + 262144);                    //  128 B
    unsigned short* Xd       = (unsigned short*)(ws + 327680);         //  ~25 MB
    unsigned short* w1t      = (unsigned short*)(ws + 33554432ull);    //  64 MB
    unsigned short* w2t      = (unsigned short*)(ws + 100663296ull);   //  64 MB
    unsigned short* hbuf     = (unsigned short*)(ws + 167772160ull);   //  96 MB  (total 256 MB)

    dim3 blk(256);
    k_transpose<<<dim3(F_ / 32, D_ / 32, E_), blk, 0, stream>>>(w1, w1t, D_, F_);
    k_transpose<<<dim3(D_ / 32, F_ / 32, E_), blk, 0, stream>>>(w2, w2t, F_, D_);
    k_router<<<dim3(NT_ / 4), blk, 0, stream>>>(hs, gw, logits, eidx, tp);
    k_scan<<<dim3(B_), blk, 0, stream>>>(eidx, slot, tok_list, counts, eif);
    k_dispatch<<<dim3(G_ * CP_ / 4), blk, 0, stream>>>(hs, tok_list, counts, Xd);
    k_ffn1<<<dim3(F_ / 128, CP_ / 128, G_), blk, 0, stream>>>(Xd, w1t, counts, hbuf);
    k_ffn2<<<dim3(D_ / 128, CP_ / 128, G_), blk, 0, stream>>>(hbuf, w2t, counts, tok_list, tp, out);
    k_pass<<<dim3(NT_ / 4), blk, 0, stream>>>(hs, slot, tp, out);
}

// Round 2
// 598.902 us; speedup vs baseline: 1.0254x; 1.0254x over previous
//
#include <hip/hip_runtime.h>

#define B_  4
#define S_  2048
#define D_  1024
#define F_  4096
#define E_  8
#define C_  320
#define CP_ 384            // padded capacity (3 x 128 tiles)
#define NT_ (B_*S_)        // 8192 tokens
#define G_  (B_*E_)        // 32 (batch, expert) groups

typedef short bf16x8 __attribute__((ext_vector_type(8)));
typedef float f32x4  __attribute__((ext_vector_type(4)));

using gptr_t = const __attribute__((address_space(1))) void*;
using lptr_t = __attribute__((address_space(3))) void*;

__device__ static inline void gll16(const void* g, void* l) {
    __builtin_amdgcn_global_load_lds((gptr_t)g, (lptr_t)l, 16, 0, 0);
}

// fp32 -> bf16 round-to-nearest-even (finite inputs only)
__device__ static inline unsigned short f2b(float f) {
    unsigned int u = __float_as_uint(f);
    u += 0x7fffu + ((u >> 16) & 1u);
    return (unsigned short)(u >> 16);
}

// ---------------- fused fp32->bf16 convert + transpose ----------------
// in: [e][R][Cc] fp32 row-major ; out: [e][Cc][R] bf16 row-major
// 64x64 tile; coalesced float4 reads, coalesced uint4 (16B) writes.
__global__ __launch_bounds__(256) void k_convT(const float* __restrict__ in,
                                               unsigned short* __restrict__ out,
                                               int R, int Cc) {
    __shared__ unsigned short ld[64][66];   // stride 66: 2-way write conflicts (free)
    int e = blockIdx.z;
    const float* src = in + (size_t)e * R * Cc;
    unsigned short* dst = out + (size_t)e * R * Cc;
    int c0 = blockIdx.x * 64, r0 = blockIdx.y * 64;
    int t = threadIdx.x;

    // phase 1: read 64 rows x 64 cols fp32, convert, scatter into LDS transposed
    int rr = t >> 4;          // 0..15
    int cg = t & 15;          // col group, 4 floats each
#pragma unroll
    for (int p = 0; p < 4; p++) {
        int row = p * 16 + rr;
        float4 v = *(const float4*)(src + (size_t)(r0 + row) * Cc + c0 + cg * 4);
        ld[cg * 4 + 0][row] = f2b(v.x);
        ld[cg * 4 + 1][row] = f2b(v.y);
        ld[cg * 4 + 2][row] = f2b(v.z);
        ld[cg * 4 + 3][row] = f2b(v.w);
    }
    __syncthreads();

    // phase 2: write out 64 transposed rows, 16B per lane
    int cc = t >> 3;          // 0..31
    int rg = t & 7;           // 8 bf16 each
#pragma unroll
    for (int p = 0; p < 2; p++) {
        int col = p * 32 + cc;
        const unsigned* lp = (const unsigned*)&ld[col][rg * 8];  // 4B-aligned
        uint4 w;
        w.x = lp[0]; w.y = lp[1]; w.z = lp[2]; w.w = lp[3];
        *(uint4*)(dst + (size_t)(c0 + col) * R + r0 + rg * 8) = w;
    }
}

// ---------------- router: logits + softmax top-1 ----------------
__global__ __launch_bounds__(256) void k_router(const float* __restrict__ hs,
                                                const float* __restrict__ gw,
                                                float* __restrict__ logits,
                                                int* __restrict__ eidx,
                                                float* __restrict__ tp) {
    int tok  = (int)((blockIdx.x * 256 + threadIdx.x) >> 6);   // one wave per token
    int lane = threadIdx.x & 63;
    const float* x = hs + (size_t)tok * D_;
    double acc[E_];
#pragma unroll
    for (int e = 0; e < E_; e++) acc[e] = 0.0;
    for (int i = 0; i < 16; i++) {
        float xv = x[lane + 64 * i];
#pragma unroll
        for (int e = 0; e < E_; e++)
            acc[e] += (double)xv * (double)gw[e * D_ + lane + 64 * i];
    }
#pragma unroll
    for (int e = 0; e < E_; e++) {
#pragma unroll
        for (int off = 32; off > 0; off >>= 1)
            acc[e] += __shfl_xor(acc[e], off, 64);
    }
    if (lane == 0) {
        float l[E_];
        float mx = -1e30f; int am = 0;
#pragma unroll
        for (int e = 0; e < E_; e++) {
            l[e] = (float)acc[e];
            if (l[e] > mx) { mx = l[e]; am = e; }   // strict > : first max wins (matches argmax)
        }
        float se = 0.f;
#pragma unroll
        for (int e = 0; e < E_; e++) se += __expf(l[e] - mx);
        tp[tok]   = 1.0f / se;     // top prob = exp(mx-mx)/sum
        eidx[tok] = am;
#pragma unroll
        for (int e = 0; e < E_; e++) logits[(size_t)tok * E_ + e] = l[e];
    }
}

// ---------------- capacity scan: slot assignment per batch ----------------
__global__ __launch_bounds__(256) void k_scan(const int* __restrict__ eidx,
                                              int* __restrict__ slot,
                                              int* __restrict__ tok_list,
                                              int* __restrict__ counts,
                                              float* __restrict__ eif) {
    int b = blockIdx.x;
    __shared__ int cCnt[32][E_];
    __shared__ int cBase[32][E_];
    int t = threadIdx.x, wv = t >> 6, lane = t & 63;
    const int* eb = eidx + b * S_;
    for (int c = wv; c < 32; c += 4) {
        int e = eb[c * 64 + lane];
#pragma unroll
        for (int x = 0; x < E_; x++) {
            unsigned long long m = __ballot(e == x);
            if (lane == 0) cCnt[c][x] = __popcll(m);
        }
    }
    __syncthreads();
    if (t < E_) {
        int s = 0;
        for (int c = 0; c < 32; c++) { cBase[c][t] = s; s += cCnt[c][t]; }
        counts[b * E_ + t] = s;
    }
    __syncthreads();
    for (int c = wv; c < 32; c += 4) {
        int s_tok = c * 64 + lane;
        int e = eb[s_tok];
        unsigned long long lowmask = (1ull << lane) - 1ull;
        int rank = 0;
#pragma unroll
        for (int x = 0; x < E_; x++) {
            unsigned long long m = __ballot(e == x);
            if (x == e) rank = __popcll(m & lowmask);
        }
        int pos = cBase[c][e] + rank;
        int assigned = (pos < C_);
        slot[b * S_ + s_tok] = assigned ? pos : C_;
        if (assigned) tok_list[(b * E_ + e) * C_ + pos] = s_tok;
        eif[b * S_ + s_tok] = assigned ? (float)e : 0.0f;
    }
}

// ---------------- dispatch: gather tokens -> bf16 Xd[g][CP_][D_] ----------------
__global__ __launch_bounds__(256) void k_dispatch(const float* __restrict__ hs,
                                                  const int* __restrict__ tok_list,
                                                  const int* __restrict__ counts,
                                                  unsigned short* __restrict__ Xd) {
    int w    = (int)((blockIdx.x * 256 + threadIdx.x) >> 6);  // one wave per row
    int lane = threadIdx.x & 63;
    int g = w / CP_, row = w % CP_;
    int b = g >> 3;
    int n = min(counts[g], C_);
    unsigned short* drow = Xd + ((size_t)g * CP_ + row) * D_;
    if (row < n) {
        int ts = tok_list[g * C_ + row];
        const float* src = hs + ((size_t)b * S_ + ts) * D_;
#pragma unroll
        for (int i = 0; i < 2; i++) {
            int c0 = (lane + 64 * i) * 8;
            float4 v0 = *(const float4*)(src + c0);
            float4 v1 = *(const float4*)(src + c0 + 4);
            uint4 pk;
            pk.x = (unsigned)f2b(v0.x) | ((unsigned)f2b(v0.y) << 16);
            pk.y = (unsigned)f2b(v0.z) | ((unsigned)f2b(v0.w) << 16);
            pk.z = (unsigned)f2b(v1.x) | ((unsigned)f2b(v1.y) << 16);
            pk.w = (unsigned)f2b(v1.z) | ((unsigned)f2b(v1.w) << 16);
            *(uint4*)(drow + c0) = pk;
        }
    } else {
        uint4 z = {0u, 0u, 0u, 0u};
#pragma unroll
        for (int i = 0; i < 2; i++)
            *(uint4*)(drow + (lane + 64 * i) * 8) = z;
    }
}

// ---------------- GEMM1: h = silu(Xd @ w1t^T) , bf16 out ----------------
__global__ __launch_bounds__(256) void k_ffn1(const unsigned short* __restrict__ Xd,
                                              const unsigned short* __restrict__ w1t,
                                              const int* __restrict__ counts,
                                              unsigned short* __restrict__ h) {
    // expert-major dispatch order: 4 consecutive z share one expert's weights
    int zz = blockIdx.z;
    int g = (zz & 3) * 8 + (zz >> 2);
    int n_tok = min(counts[g], C_);
    int m0 = blockIdx.y * 128;
    if (m0 >= n_tok) return;               // block-uniform early exit
    int n0 = blockIdx.x * 128;
    int e = g & 7;

    __shared__ unsigned short As[128 * 32];
    __shared__ unsigned short Bs[128 * 32];
    int t = threadIdx.x, lane = t & 63, wv = t >> 6, wm = wv >> 1, wn = wv & 1;

    const unsigned short* Ap = Xd  + (size_t)g * CP_ * D_ + (size_t)(m0 + (t >> 2)) * D_ + (t & 3) * 8;
    const unsigned short* Bp = w1t + (size_t)e * F_ * D_  + (size_t)(n0 + (t >> 2)) * D_ + (t & 3) * 8;

    f32x4 acc[4][4];
    f32x4 z = {0.f, 0.f, 0.f, 0.f};
#pragma unroll
    for (int i = 0; i < 4; i++)
#pragma unroll
        for (int j = 0; j < 4; j++) acc[i][j] = z;

    int ar = (wm * 64 + (lane & 15)) * 32 + (lane >> 4) * 8;
    int br = (wn * 64 + (lane & 15)) * 32 + (lane >> 4) * 8;

    for (int kt = 0; kt < D_; kt += 32) {
        __syncthreads();
        gll16(Ap,            (char*)As + wv * 1024);
        gll16(Ap + 64 * D_,  (char*)As + 4096 + wv * 1024);
        gll16(Bp,            (char*)Bs + wv * 1024);
        gll16(Bp + 64 * D_,  (char*)Bs + 4096 + wv * 1024);
        Ap += 32; Bp += 32;
        __syncthreads();
        bf16x8 a[4], bq[4];
#pragma unroll
        for (int i = 0; i < 4; i++) a[i]  = *(const bf16x8*)&As[ar + i * 512];
#pragma unroll
        for (int j = 0; j < 4; j++) bq[j] = *(const bf16x8*)&Bs[br + j * 512];
#pragma unroll
        for (int i = 0; i < 4; i++)
#pragma unroll
            for (int j = 0; j < 4; j++)
                acc[i][j] = __builtin_amdgcn_mfma_f32_16x16x32_bf16(a[i], bq[j], acc[i][j], 0, 0, 0);
    }

    unsigned short* hb = h + (size_t)g * CP_ * F_;
    int crow = m0 + wm * 64 + (lane >> 4) * 4;
    int ccol = n0 + wn * 64 + (lane & 15);
#pragma unroll
    for (int i = 0; i < 4; i++)
#pragma unroll
        for (int r = 0; r < 4; r++) {
            int row = crow + i * 16 + r;
#pragma unroll
            for (int j = 0; j < 4; j++) {
                float v = acc[i][j][r];
                v = v / (1.0f + __expf(-v));        // silu
                hb[(size_t)row * F_ + ccol + j * 16] = f2b(v);
            }
        }
}

// ---------------- GEMM2: y = h @ w2t^T, scale by top_prob, scatter ----------------
__global__ __launch_bounds__(256) void k_ffn2(const unsigned short* __restrict__ h,
                                              const unsigned short* __restrict__ w2t,
                                              const int* __restrict__ counts,
                                              const int* __restrict__ tok_list,
                                              const float* __restrict__ tp,
                                              float* __restrict__ out) {
    int zz = blockIdx.z;
    int g = (zz & 3) * 8 + (zz >> 2);
    int n_tok = min(counts[g], C_);
    int m0 = blockIdx.y * 128;
    if (m0 >= n_tok) return;
    int n0 = blockIdx.x * 128;
    int b = g >> 3, e = g & 7;

    __shared__ unsigned short As[128 * 32];
    __shared__ unsigned short Bs[128 * 32];
    int t = threadIdx.x, lane = t & 63, wv = t >> 6, wm = wv >> 1, wn = wv & 1;

    const unsigned short* Ap = h   + (size_t)g * CP_ * F_ + (size_t)(m0 + (t >> 2)) * F_ + (t & 3) * 8;
    const unsigned short* Bp = w2t + (size_t)e * D_ * F_  + (size_t)(n0 + (t >> 2)) * F_ + (t & 3) * 8;

    f32x4 acc[4][4];
    f32x4 z = {0.f, 0.f, 0.f, 0.f};
#pragma unroll
    for (int i = 0; i < 4; i++)
#pragma unroll
        for (int j = 0; j < 4; j++) acc[i][j] = z;

    int ar = (wm * 64 + (lane & 15)) * 32 + (lane >> 4) * 8;
    int br = (wn * 64 + (lane & 15)) * 32 + (lane >> 4) * 8;

    for (int kt = 0; kt < F_; kt += 32) {
        __syncthreads();
        gll16(Ap,            (char*)As + wv * 1024);
        gll16(Ap + 64 * F_,  (char*)As + 4096 + wv * 1024);
        gll16(Bp,            (char*)Bs + wv * 1024);
        gll16(Bp + 64 * F_,  (char*)Bs + 4096 + wv * 1024);
        Ap += 32; Bp += 32;
        __syncthreads();
        bf16x8 a[4], bq[4];
#pragma unroll
        for (int i = 0; i < 4; i++) a[i]  = *(const bf16x8*)&As[ar + i * 512];
#pragma unroll
        for (int j = 0; j < 4; j++) bq[j] = *(const bf16x8*)&Bs[br + j * 512];
#pragma unroll
        for (int i = 0; i < 4; i++)
#pragma unroll
            for (int j = 0; j < 4; j++)
                acc[i][j] = __builtin_amdgcn_mfma_f32_16x16x32_bf16(a[i], bq[j], acc[i][j], 0, 0, 0);
    }

    int crow = m0 + wm * 64 + (lane >> 4) * 4;
    int ccol = n0 + wn * 64 + (lane & 15);
#pragma unroll
    for (int i = 0; i < 4; i++)
#pragma unroll
        for (int r = 0; r < 4; r++) {
            int row = crow + i * 16 + r;
            if (row < n_tok) {
                int ts = tok_list[g * C_ + row];
                float sc = tp[b * S_ + ts];
                float* orow = out + ((size_t)b * S_ + ts) * D_ + ccol;
#pragma unroll
                for (int j = 0; j < 4; j++)
                    orow[j * 16] = sc * acc[i][j][r];
            }
        }
}

// ---------------- passthrough for dropped tokens ----------------
__global__ __launch_bounds__(256) void k_pass(const float* __restrict__ hs,
                                              const int* __restrict__ slot,
                                              const float* __restrict__ tp,
                                              float* __restrict__ out) {
    int tok  = (int)((blockIdx.x * 256 + threadIdx.x) >> 6);
    int lane = threadIdx.x & 63;
    if (slot[tok] < C_) return;            // assigned: written by k_ffn2
    float sc = tp[tok];
    const float* src = hs + (size_t)tok * D_;
    float* dst = out + (size_t)tok * D_;
#pragma unroll
    for (int i = 0; i < 4; i++) {
        float4 v = *(const float4*)(src + (lane + 64 * i) * 4);
        v.x *= sc; v.y *= sc; v.z *= sc; v.w *= sc;
        *(float4*)(dst + (lane + 64 * i) * 4) = v;
    }
}

extern "C" void kernel_launch(void* const* d_in, const int* in_sizes, int n_in,
                              void* d_out, int out_size, void* d_ws, size_t ws_size,
                              hipStream_t stream) {
    const float* hs = (const float*)d_in[0];
    const float* gw = (const float*)d_in[1];
    const float* w1 = (const float*)d_in[2];
    const float* w2 = (const float*)d_in[3];

    float* out    = (float*)d_out;                       // [B,S,D] fp32
    float* logits = out + (size_t)NT_ * D_;              // [B,S,E] fp32
    float* eif    = logits + (size_t)NT_ * E_;           // [B,S]

    char* ws = (char*)d_ws;
    int*            eidx     = (int*)(ws + 0);
    int*            slot     = (int*)(ws + 65536);
    float*          tp       = (float*)(ws + 131072);
    int*            tok_list = (int*)(ws + 196608);
    int*            counts   = (int*)(ws + 262144);
    unsigned short* Xd       = (unsigned short*)(ws + 327680);
    unsigned short* w1t      = (unsigned short*)(ws + 33554432ull);
    unsigned short* w2t      = (unsigned short*)(ws + 100663296ull);
    unsigned short* hbuf     = (unsigned short*)(ws + 167772160ull);

    dim3 blk(256);
    k_convT<<<dim3(F_ / 64, D_ / 64, E_), blk, 0, stream>>>(w1, w1t, D_, F_);
    k_convT<<<dim3(D_ / 64, F_ / 64, E_), blk, 0, stream>>>(w2, w2t, F_, D_);
    k_router<<<dim3(NT_ / 4), blk, 0, stream>>>(hs, gw, logits, eidx, tp);
    k_scan<<<dim3(B_), blk, 0, stream>>>(eidx, slot, tok_list, counts, eif);
    k_dispatch<<<dim3(G_ * CP_ / 4), blk, 0, stream>>>(hs, tok_list, counts, Xd);
    k_ffn1<<<dim3(F_ / 128, CP_ / 128, G_), blk, 0, stream>>>(Xd, w1t, counts, hbuf);
    k_ffn2<<<dim3(D_ / 128, CP_ / 128, G_), blk, 0, stream>>>(hbuf, w2t, counts, tok_list, tp, out);
    k_pass<<<dim3(NT_ / 4), blk, 0, stream>>>(hs, slot, tp, out);
}